// Round 39
// baseline (187.882 us; speedup 1.0000x reference)
//
#include <hip/hip_runtime.h>
#include <hip/hip_bf16.h>

// ResnetBlockDDPMpp_Adagn: B=8, CIN=COUT=256, H=W=64, G=32, K=3
// Round 39 (on R38 pass, 185.7us — best; 11 consecutive matched tail wins):
//  - R38 lesson: tproj blocks were prep's critical-path stragglers (512
//    serial exp/thread); fixing them was -17.5us, not -3. Per-block
//    imbalance inside multi-role kernels >> aggregate counters.
//  - Tail attack #11: conv1 was LDS-capped at 2 blk/CU (59.9KB) while
//    latency-bound (MfmaUtil 21%, occ 38%). Shave LDS -> 3 blk/CU:
//    (a) aw stride 272->264 ushorts (528B, 16B-aligned; dword-stride = 4
//        mod 32 -> 2 lanes/bank on b128 = free);
//    (b) alias fold scratch fls/flq (conv1) and pacc (offset) into aw
//        (temporally disjoint; offset gets one extra barrier before the
//        pacc write). conv1 59.9->52.9KB, offset 59.6->52.6KB -> 3 blk/CU.
//    __launch_bounds__(512,6). No arithmetic change (bit-identical).
//  - deform + prep + h0 byte-identical to R38.

#define EPSV 1e-6f

typedef short    s16x8 __attribute__((ext_vector_type(8)));   // raw 8x16b storage
typedef _Float16 h16x8 __attribute__((ext_vector_type(8)));   // fp16 math/MFMA
typedef float    f32x4 __attribute__((ext_vector_type(4)));

__device__ __forceinline__ float silu_f(float v){ return v / (1.f + __expf(-v)); }
__device__ __forceinline__ unsigned short f2h(float f){
  _Float16 h = (_Float16)f; unsigned short u; __builtin_memcpy(&u, &h, 2); return u;
}
__device__ __forceinline__ float h2f(unsigned short u){
  _Float16 h; __builtin_memcpy(&h, &u, 2); return (float)h;
}

// ---------------- ws layout (float units) ----------------
#define WS_H0B     0            // 8*4096*256 fp16
#define WS_H1B     4194304      // 8*4096*256 fp16
#define WS_OFFT    8388608      // 8*4096*27 fp32
#define WS_WTD     9273344      // dcn fp16 [9][32][256][8]
#define WS_WTC     9568256      // conv1 fp16 same
#define WS_OFFWTB  9863168      // offw fp16 [9][32][32][8]
#define WS_STYLE0  9900032
#define WS_STYLE1  9904128
#define WS_TPROJ   9908224
#define WS_MU0     9910272
#define WS_RS0     9910528
#define WS_GN1P    9911296      // 8 b x 128 pblk x 64 = 65536 floats
#define WS_XH      9976832      // x as fp16 NCHW: 8388608 ushort = 4194304 floats
// end 14,171,136 floats = 56.7 MB (R4 proved 73.3MB OK)

#define SSTR 272   // deform samp stride (ushorts): 544B, 16B-aligned
#define ASTR 264   // offset/conv1 halo stride (ushorts): 528B, 16B-aligned

// ---------- reductions ----------
__device__ __forceinline__ void block_reduce2(float& s, float& q){
  for (int off = 32; off > 0; off >>= 1) {
    s += __shfl_down(s, off, 64);
    q += __shfl_down(q, off, 64);
  }
  __shared__ float ss[4], qs[4];
  int wid = threadIdx.x >> 6, lane = threadIdx.x & 63;
  if (lane == 0) { ss[wid] = s; qs[wid] = q; }
  __syncthreads();
  if (threadIdx.x == 0) { s = ss[0]+ss[1]+ss[2]+ss[3]; q = qs[0]+qs[1]+qs[2]+qs[3]; }
}

// ---------- prep: coalesced weight packs + tiny GEMMs + gn0 stats + xh ----------
// grid 712: [0,64) dcn pack | [64,128) conv1 pack | [128,416) offw pack
//          [416,432) style0 | [432,448) style1 | [448,456) tproj | [456,712) gn0+xh
__global__ __launch_bounds__(256) void prep_kernel(
    const float* __restrict__ zemb, const float* __restrict__ temb,
    const float* __restrict__ g0w, const float* __restrict__ g0b,
    const float* __restrict__ g1w, const float* __restrict__ g1b,
    const float* __restrict__ d0w, const float* __restrict__ d0b,
    const float* __restrict__ dcn_w, const float* __restrict__ c1w,
    const float* __restrict__ offw, const float* __restrict__ x,
    unsigned short* __restrict__ wtd, unsigned short* __restrict__ wtc,
    unsigned short* __restrict__ offwtb,
    float* __restrict__ style0, float* __restrict__ style1, float* __restrict__ tproj,
    float* __restrict__ mu0, float* __restrict__ rs0,
    unsigned short* __restrict__ xh)
{
  __shared__ unsigned short lbuf[9216];   // 18KB: 4 o-rows of [256 c][9 k] fp16
  int blk = blockIdx.x, t = threadIdx.x;
  if (blk < 128) {                        // coalesced pack: dcn (blk<64) / conv1
    const float* src = (blk < 64) ? dcn_w : c1w;
    unsigned short* dst = (blk < 64) ? wtd : wtc;
    int o0 = (blk & 63) * 4;
    const float* sp = src + (size_t)o0 * 2304;   // 4 o-rows = 9216 floats, contiguous
    #pragma unroll
    for (int i = 0; i < 36; ++i) {        // phase 1: contiguous read -> LDS fp16
      int idx = i*256 + t;
      lbuf[idx] = f2h(sp[idx]);
    }
    __syncthreads();
    #pragma unroll
    for (int i = 0; i < 36; ++i) {        // phase 2: packed write, 64B runs
      int idx = i*256 + t;
      int kc8 = idx >> 5, m = idx & 31;
      int o = m >> 3, j = m & 7;
      int k = kc8 / 32, c8 = kc8 & 31;
      dst[((size_t)(k*32 + c8)*256 + (o0 + o))*8 + j] = lbuf[(o*256 + c8*8 + j)*9 + k];
    }
  } else if (blk < 416) {                 // offw pack: [9][32 c8][32 o][8 j], oc>=27 -> 0
    int e = (blk-128)*256 + t;            // 73728 elems
    int j = e & 7, o = (e >> 3) & 31, c8 = (e >> 8) & 31, k = e >> 13;
    int c = c8*8 + j;
    offwtb[e] = (o < 27) ? f2h(offw[((o*256 + c)*9) + k]) : (unsigned short)0;
  } else if (blk < 432) {                 // style0 = zemb @ g0w.T + g0b (8x512)
    int e = (blk-416)*256 + t; int b = e >> 9, j = e & 511;
    float s = g0b[j];
    const float* z = zemb + b*256; const float* w = g0w + j*256;
    for (int i = 0; i < 256; ++i) s += z[i]*w[i];
    style0[e] = s;
  } else if (blk < 448) {                 // style1
    int e = (blk-432)*256 + t; int b = e >> 9, j = e & 511;
    float s = g1b[j];
    const float* z = zemb + b*256; const float* w = g1w + j*256;
    for (int i = 0; i < 256; ++i) s += z[i]*w[i];
    style1[e] = s;
  } else if (blk < 456) {                 // tproj = silu(temb) @ d0w.T + d0b (one b/block)
    int b = blk - 448;
    float* st = (float*)lbuf;             // reuse 2KB of lbuf for silu(temb[b])
    const float* tb = temb + b*512;
    st[t]       = silu_f(tb[t]);
    st[t + 256] = silu_f(tb[t + 256]);
    __syncthreads();
    int o = t;
    float s = d0b[o];
    const float* w = d0w + o*512;
    for (int i = 0; i < 512; ++i) s += st[i]*w[i];
    tproj[b*256 + o] = s;
  } else {                                // gn0 stats + xh emit: blk2 = b*32+g (NCHW)
    int blk2 = blk - 456;                 // 256 blocks
    const float4* p4 = (const float4*)(x + (size_t)blk2*32768);
    unsigned short* xo = xh + (size_t)blk2*32768;
    float s = 0.f, q = 0.f;
    for (int i = t*2; i < 8192; i += 512) {   // 2 float4 reads + 1 s16x8 store
      float4 v0 = p4[i], v1 = p4[i+1];
      s += v0.x+v0.y+v0.z+v0.w + v1.x+v1.y+v1.z+v1.w;
      q += v0.x*v0.x + v0.y*v0.y + v0.z*v0.z + v0.w*v0.w
         + v1.x*v1.x + v1.y*v1.y + v1.z*v1.z + v1.w*v1.w;
      s16x8 pk;
      pk[0] = (short)f2h(v0.x); pk[1] = (short)f2h(v0.y);
      pk[2] = (short)f2h(v0.z); pk[3] = (short)f2h(v0.w);
      pk[4] = (short)f2h(v1.x); pk[5] = (short)f2h(v1.y);
      pk[6] = (short)f2h(v1.z); pk[7] = (short)f2h(v1.w);
      *(s16x8*)(xo + (size_t)i*4) = pk;
    }
    block_reduce2(s, q);
    if (t == 0) {
      float m = s * (1.f/32768.f);
      float var = q * (1.f/32768.f) - m*m;
      mu0[blk2] = m; rs0[blk2] = rsqrtf(var + EPSV);
    }
  }
}

// ---------- h0 = silu(adagn(xh)) NCHW -> NHWC fp16, vectorized ----------
#define HSTR 72    // LDS row stride (ushorts): 144B, 16B-aligned
__global__ __launch_bounds__(256) void h0_kernel(
    const unsigned short* __restrict__ xh, const float* __restrict__ style0,
    const float* __restrict__ mu, const float* __restrict__ rs,
    unsigned short* __restrict__ h0h)
{
  int blk = blockIdx.x;          // b(8) x ptile(64) x ctile(8)
  int b  = blk >> 9;
  int pt = (blk >> 3) & 63;
  int ct = blk & 7;
  __shared__ unsigned short sh[32*HSTR];   // 4.5KB fp16 tile
  int p0 = pt*64, c0 = ct*32;
  int t = threadIdx.x;
  {                              // read: 1 x ushort8 per thread (16B/lane)
    int ci = t >> 3;             // 0..31
    int pb = t & 7;              // p octet
    int c  = c0 + ci;
    s16x8 v8 = *(const s16x8*)&xh[((size_t)(b*256 + c))*4096 + p0 + pb*8];
    int g = c >> 3;
    float m  = mu[b*32+g], r = rs[b*32+g];
    float ga = style0[b*512 + c], be = style0[b*512 + 256 + c];
    s16x8 o8;
    #pragma unroll
    for (int j = 0; j < 8; ++j) {
      float v = h2f((unsigned short)v8[j]);
      float u = ga * (v - m) * r + be;
      o8[j] = (short)f2h(silu_f(u));
    }
    *(s16x8*)&sh[ci*HSTR + pb*8] = o8;
  }
  __syncthreads();
  {                              // write: 1 x ushort8 per thread (16B/lane)
    int p  = t >> 2;             // 0..63
    int co = (t & 3)*8;          // c octet
    s16x8 o8;
    #pragma unroll
    for (int j = 0; j < 8; ++j) o8[j] = (short)sh[(co + j)*HSTR + p];
    *(s16x8*)&h0h[((size_t)(b*4096 + p0 + p))*256 + c0 + co] = o8;
  }
}

// ---------- offset conv MFMA (fp16): 512 thr, kc-split waves, 3 blk/CU ----------
__global__ __launch_bounds__(512, 6) void offset_mfma_kernel(
    const unsigned short* __restrict__ h0h, const unsigned short* __restrict__ wt,
    const float* __restrict__ off_b, float* __restrict__ off_t)
{
  int bid = blockIdx.x;
  int b  = bid & 7;                            // XCD swizzle
  int p0 = (bid >> 3) * 32;
  int y = p0 >> 6, xb = p0 & 63;
  int t = threadIdx.x;                         // 0..511
  int lane = t & 63, wv = t >> 6;              // 8 waves
  int r = lane & 15, g = lane >> 4;

  __shared__ __attribute__((aligned(16))) unsigned short aw[3*34*ASTR]; // 52.6KB
  f32x4 (*pacc)[64] = (f32x4(*)[64])aw;        // aliased: used only after aw dead

  const unsigned short* hbase = h0h + (size_t)b*1048576;
  for (int idx = t; idx < 3264; idx += 512) {
    int row = idx / 1088, rem = idx - row*1088;
    int px = rem >> 5, c8 = rem & 31;
    int yy = y + row - 1, xx = xb - 1 + px;
    s16x8 v = {0,0,0,0,0,0,0,0};
    if (yy >= 0 && yy < 64 && xx >= 0 && xx < 64)
      v = *(const s16x8*)&hbase[((size_t)yy*64 + xx)*256 + c8*8];
    *(s16x8*)&aw[(row*34 + px)*ASTR + c8*8] = v;
  }
  __syncthreads();

  int m = wv & 1, n = (wv >> 1) & 1, h = wv >> 2;   // tile (px half, oc half), kc half
  f32x4 acc = {0.f,0.f,0.f,0.f};
  for (int k = 0; k < 9; ++k) {
    int ky = k/3, kxo = k%3;
    const unsigned short* abase = &aw[(ky*34)*ASTR];
    const unsigned short* wk = wt + (size_t)k*8192;   // [32 c8][32 o][8]
    #pragma unroll
    for (int kc2 = 0; kc2 < 4; ++kc2) {
      int kc = h*4 + kc2;
      h16x8 a  = *(const h16x8*)&abase[(kxo + m*16 + r)*ASTR + kc*32 + g*8];
      h16x8 bf = *(const h16x8*)&wk[(size_t)((kc*4 + g)*32 + n*16 + r)*8];
      acc = __builtin_amdgcn_mfma_f32_16x16x32_f16(a, bf, acc, 0, 0, 0);
    }
  }

  int tile = wv & 3;
  __syncthreads();                             // aw dead everywhere before alias write
  if (h == 1) pacc[tile][lane] = acc;
  __syncthreads();
  if (h == 0) {
    acc = acc + pacc[tile][lane];                // fixed 2-term association
    int oc = n*16 + r;
    if (oc < 27) {
      float bs = off_b[oc];
      #pragma unroll
      for (int j = 0; j < 4; ++j) {
        int px = m*16 + g*4 + j;
        off_t[((size_t)(b*4096) + p0 + px)*27 + oc] = acc[j] + bs;
      }
    }
  }
}

// ---------- deformable conv (fp16): M=32, pre[8] resident, fused gn1 partials ----------
__global__ __launch_bounds__(512, 2) void deform_mfma_kernel(
    const unsigned short* __restrict__ h0h, const float* __restrict__ off_t,
    const unsigned short* __restrict__ wt, const float* __restrict__ dcn_b,
    const float* __restrict__ tproj, unsigned short* __restrict__ h1h,
    float* __restrict__ part)
{
  int bid = blockIdx.x;                        // 1024 blocks
  int b  = bid & 7;                            // XCD swizzle (1024 % 8 == 0)
  int p0 = (bid >> 3) * 32;                    // 32 px, same row
  int t = threadIdx.x;                         // 0..511
  int lane = t & 63, wv = t >> 6;              // 8 waves
  int r = lane & 15, g = lane >> 4;

  __shared__ unsigned short samp[2][32*SSTR];  // dbuf 34.8KB
  __shared__ int    pki[288];
  __shared__ float4 pkw[288];                  // total 40.6KB -> 4 blk/CU

  for (int tp = t; tp < 288; tp += 512) {      // 32 px x 9 taps
    int i = tp / 9, k = tp - i*9;
    int p = p0 + i; int y = p >> 6, xq = p & 63;
    const float* ob = off_t + ((size_t)(b*4096) + p)*27;
    float dy = ob[2*k], dx = ob[2*k+1];
    float mask = 1.f / (1.f + __expf(-ob[18+k]));
    float py = dy + (float)(k/3 + y - 1);
    float px = dx + (float)(k%3 + xq - 1);
    float fy0 = floorf(py), fx0 = floorf(px);
    float wy1 = py - fy0, wx1 = px - fx0;
    int y0 = (int)fy0, x0 = (int)fx0, y1 = y0+1, x1 = x0+1;
    float vy0 = (y0 >= 0 && y0 < 64) ? 1.f : 0.f;
    float vy1 = (y1 >= 0 && y1 < 64) ? 1.f : 0.f;
    float vx0 = (x0 >= 0 && x0 < 64) ? 1.f : 0.f;
    float vx1 = (x1 >= 0 && x1 < 64) ? 1.f : 0.f;
    int iy0 = min(max(y0,0),63), ix0 = min(max(x0,0),63);
    int iy1 = min(max(y1,0),63), ix1 = min(max(x1,0),63);
    pki[tp] = iy0 | (ix0 << 8) | (iy1 << 16) | (ix1 << 24);
    float4 w;
    w.x = (1.f-wy1)*(1.f-wx1)*vy0*vx0*mask;
    w.y = (1.f-wy1)*wx1      *vy0*vx1*mask;
    w.z = wy1      *(1.f-wx1)*vy1*vx0*mask;
    w.w = wy1      *wx1      *vy1*vx1*mask;
    pkw[tp] = w;
  }
  __syncthreads();

  f32x4 zero4 = {0.f,0.f,0.f,0.f};
  f32x4 acc[2][2];
  #pragma unroll
  for (int m = 0; m < 2; ++m) { acc[m][0] = zero4; acc[m][1] = zero4; }

  const unsigned short* hb = h0h + (size_t)b*1048576;
  int px = t >> 4;                             // 16 threads per pixel (32 px)
  int ci = (t & 15) * 16;                      // 16 contiguous channels each
  int o_base = wv*32 + r;                      // 8 waves x UNIQUE 32-out slice

  h16x8 pre[8];                                // 4 corners x 16ch = 32 VGPR
  auto loadk = [&](int kk) {
    int tp = px*9 + kk;
    int pk = pki[tp];
    int iy0 = pk & 255, ix0 = (pk >> 8) & 255, iy1 = (pk >> 16) & 255, ix1 = (pk >> 24) & 255;
    const h16x8* q00 = (const h16x8*)(hb + ((size_t)iy0*64 + ix0)*256 + ci);
    const h16x8* q01 = (const h16x8*)(hb + ((size_t)iy0*64 + ix1)*256 + ci);
    const h16x8* q10 = (const h16x8*)(hb + ((size_t)iy1*64 + ix0)*256 + ci);
    const h16x8* q11 = (const h16x8*)(hb + ((size_t)iy1*64 + ix1)*256 + ci);
    pre[0] = q00[0]; pre[1] = q00[1];
    pre[2] = q01[0]; pre[3] = q01[1];
    pre[4] = q10[0]; pre[5] = q10[1];
    pre[6] = q11[0]; pre[7] = q11[1];
  };

  loadk(0);
  for (int k = 0; k < 9; ++k) {
    { // pk-fma weighted sum from prefetch regs -> LDS buf k&1
      int tp = px*9 + k;
      float4 w = pkw[tp];
      _Float16 w00 = (_Float16)w.x, w01 = (_Float16)w.y;
      _Float16 w10 = (_Float16)w.z, w11 = (_Float16)w.w;
      unsigned short* sp = &samp[k & 1][px*SSTR + ci];
      #pragma unroll
      for (int ch = 0; ch < 2; ++ch) {
        h16x8 o = pre[ch]*w00 + pre[2+ch]*w01 + pre[4+ch]*w10 + pre[6+ch]*w11;
        *(h16x8*)(sp + ch*8) = o;
      }
    }
    if (k < 8) loadk(k+1);                     // pre[8] stays resident
    asm volatile("s_waitcnt lgkmcnt(0)" ::: "memory");
    __builtin_amdgcn_s_barrier();

    const unsigned short* sb = samp[k & 1];
    const unsigned short* wk = wt + (size_t)k*65536;   // [32][256][8] this tap
    #pragma unroll
    for (int kc = 0; kc < 8; ++kc) {
      h16x8 a0 = *(const h16x8*)&sb[(     r)*SSTR + kc*32 + g*8];
      h16x8 a1 = *(const h16x8*)&sb[(16 + r)*SSTR + kc*32 + g*8];
      const unsigned short* wb = wk + (size_t)(kc*4 + g)*2048 + o_base*8;
      h16x8 b0 = *(const h16x8*)&wb[  0*8];
      h16x8 b1 = *(const h16x8*)&wb[ 16*8];
      acc[0][0] = __builtin_amdgcn_mfma_f32_16x16x32_f16(a0, b0, acc[0][0], 0, 0, 0);
      acc[0][1] = __builtin_amdgcn_mfma_f32_16x16x32_f16(a0, b1, acc[0][1], 0, 0, 0);
      acc[1][0] = __builtin_amdgcn_mfma_f32_16x16x32_f16(a1, b0, acc[1][0], 0, 0, 0);
      acc[1][1] = __builtin_amdgcn_mfma_f32_16x16x32_f16(a1, b1, acc[1][1], 0, 0, 0);
    }
    // no second barrier: next tap writes the other buffer (WAR safe)
  }

  // epilogue: h1 write + fused gn1 partials (on the exact fp16-rounded values)
  float gs[2], gq[2];
  #pragma unroll
  for (int nn = 0; nn < 2; ++nn) {
    int o = o_base + nn*16;
    float bs = dcn_b[o] + tproj[b*256 + o];
    float s = 0.f, q = 0.f;
    #pragma unroll
    for (int m = 0; m < 2; ++m)
      #pragma unroll
      for (int j = 0; j < 4; ++j) {
        int pxl = m*16 + g*4 + j;
        unsigned short hu = f2h(acc[m][nn][j] + bs);
        h1h[((size_t)(b*4096) + p0 + pxl)*256 + o] = hu;
        float f = h2f(hu);
        s += f; q += f*f;
      }
    // cross-g reduce: lanes r, r+16, r+32, r+48 (same wave), fixed order
    s += __shfl_down(s, 16, 64); s += __shfl_down(s, 32, 64);
    q += __shfl_down(q, 16, 64); q += __shfl_down(q, 32, 64);
    gs[nn] = s; gq[nn] = q;
  }
  __syncthreads();                             // all samp/pkw consumers done
  float* sred = (float*)samp;                  // reuse dead LDS (2KB needed)
  float* qred = sred + 256;
  if (g == 0) {
    #pragma unroll
    for (int nn = 0; nn < 2; ++nn) {
      int o = o_base + nn*16;
      sred[o] = gs[nn]; qred[o] = gq[nn];
    }
  }
  __syncthreads();
  if (t < 32) {                                // fold 8 channels -> group partial
    float s = 0.f, q = 0.f;
    #pragma unroll
    for (int j = 0; j < 8; ++j) { s += sred[t*8 + j]; q += qred[t*8 + j]; }
    int pblk = bid >> 3;
    part[((size_t)(b*128 + pblk))*64 + t]      = s;
    part[((size_t)(b*128 + pblk))*64 + 32 + t] = q;
  }
}

// ---------- conv1 (fp16) M=32, fused gn1-finalize, 3 blk/CU ----------
__global__ __launch_bounds__(512, 6) void conv1_mfma_kernel(
    const unsigned short* __restrict__ h1h, const float* __restrict__ style1,
    const float* __restrict__ part,
    const unsigned short* __restrict__ wt,
    const float* __restrict__ c1_b, const unsigned short* __restrict__ xh,
    float* __restrict__ out)
{
  int bid = blockIdx.x;                        // 1024 blocks
  int b  = bid & 7;                            // XCD swizzle
  int p0 = (bid >> 3) * 32;
  int y = p0 >> 6, xb = p0 & 63;
  int t = threadIdx.x;                         // 0..511
  int lane = t & 63, wv = t >> 6;              // 8 waves
  int r = lane & 15, g = lane >> 4;

  __shared__ __attribute__((aligned(16))) unsigned short aw[3*34*ASTR]; // 52.6KB
  __shared__ float smu[32], srs[32];
  float* fls = (float*)aw;                     // aliased fold scratch (4KB),
  float* flq = fls + 512;                      // dead before aw staging

  // gn1 finalize, parallel: thread (s=t>>5, g2=t&31) sums 8 block-partials
  {
    int s = t >> 5, g2 = t & 31;
    float fs = 0.f, fq = 0.f;
    #pragma unroll
    for (int c = 0; c < 8; ++c) {
      int ch = s*8 + c;
      fs += part[(b*128 + ch)*64 + g2];
      fq += part[(b*128 + ch)*64 + 32 + g2];
    }
    fls[s*32 + g2] = fs; flq[s*32 + g2] = fq;
  }
  __syncthreads();
  if (t < 32) {                                // fixed-order 16-slice reduce
    float s2 = 0.f, q2 = 0.f;
    #pragma unroll
    for (int sl = 0; sl < 16; ++sl) { s2 += fls[sl*32 + t]; q2 += flq[sl*32 + t]; }
    float m = s2 * (1.f/32768.f);
    float var = q2 * (1.f/32768.f) - m*m;
    smu[t] = m; srs[t] = rsqrtf(var + EPSV);
  }
  __syncthreads();

  const unsigned short* h1base = h1h + (size_t)b*1048576;
  for (int idx = t; idx < 3264; idx += 512) {  // 3 rows * 34 px * 32 chunks(8c)
    int row = idx / 1088, rem = idx - row*1088;
    int px = rem >> 5, c8 = rem & 31;
    int yy = y + row - 1, xx = xb - 1 + px;
    s16x8 v = {0,0,0,0,0,0,0,0};
    if (yy >= 0 && yy < 64 && xx >= 0 && xx < 64) {
      s16x8 h = *(const s16x8*)&h1base[((size_t)yy*64 + xx)*256 + c8*8];
      float m  = smu[c8], rr = srs[c8];
      #pragma unroll
      for (int j = 0; j < 8; ++j) {
        int c = c8*8 + j;
        float ga = style1[b*512 + c], be = style1[b*512 + 256 + c];
        float u = ga * (h2f((unsigned short)h[j]) - m) * rr + be;
        v[j] = (short)f2h(silu_f(u));
      }
    }
    *(s16x8*)&aw[(row*34 + px)*ASTR + c8*8] = v;
  }
  __syncthreads();

  f32x4 zero4 = {0.f,0.f,0.f,0.f};
  f32x4 acc[2][2];
  #pragma unroll
  for (int m = 0; m < 2; ++m) { acc[m][0] = zero4; acc[m][1] = zero4; }

  int o_base = wv*32 + r;                      // 8 waves x UNIQUE 32-out slice
  for (int k = 0; k < 9; ++k) {
    int ky = k/3, kxo = k%3;
    const unsigned short* abase = &aw[(ky*34)*ASTR];
    const unsigned short* wk = wt + (size_t)k*65536;
    #pragma unroll
    for (int kc = 0; kc < 8; ++kc) {
      h16x8 a0 = *(const h16x8*)&abase[(kxo +      r)*ASTR + kc*32 + g*8];
      h16x8 a1 = *(const h16x8*)&abase[(kxo + 16 + r)*ASTR + kc*32 + g*8];
      const unsigned short* wb = wk + (size_t)(kc*4 + g)*2048 + o_base*8;
      h16x8 b0 = *(const h16x8*)&wb[  0*8];
      h16x8 b1 = *(const h16x8*)&wb[ 16*8];
      acc[0][0] = __builtin_amdgcn_mfma_f32_16x16x32_f16(a0, b0, acc[0][0], 0, 0, 0);
      acc[0][1] = __builtin_amdgcn_mfma_f32_16x16x32_f16(a0, b1, acc[0][1], 0, 0, 0);
      acc[1][0] = __builtin_amdgcn_mfma_f32_16x16x32_f16(a1, b0, acc[1][0], 0, 0, 0);
      acc[1][1] = __builtin_amdgcn_mfma_f32_16x16x32_f16(a1, b1, acc[1][1], 0, 0, 0);
    }
  }

  #pragma unroll
  for (int nn = 0; nn < 2; ++nn) {
    int o = o_base + nn*16;
    float cb = c1_b[o];
    #pragma unroll
    for (int m = 0; m < 2; ++m)
      #pragma unroll
      for (int j = 0; j < 4; ++j) {
        int pxl = m*16 + g*4 + j;
        size_t oi = ((size_t)(b*256 + o))*4096 + p0 + pxl;
        out[oi] = h2f(xh[oi]) + acc[m][nn][j] + cb;
      }
  }
}

extern "C" void kernel_launch(void* const* d_in, const int* in_sizes, int n_in,
                              void* d_out, int out_size, void* d_ws, size_t ws_size,
                              hipStream_t stream) {
  const float* x    = (const float*)d_in[0];
  const float* temb = (const float*)d_in[1];
  const float* zemb = (const float*)d_in[2];
  const float* g0w  = (const float*)d_in[3];
  const float* g0b  = (const float*)d_in[4];
  const float* offw = (const float*)d_in[5];
  const float* offb = (const float*)d_in[6];
  const float* dcnw = (const float*)d_in[7];
  const float* dcnb = (const float*)d_in[8];
  const float* d0w  = (const float*)d_in[9];
  const float* d0b  = (const float*)d_in[10];
  const float* g1w  = (const float*)d_in[11];
  const float* g1b  = (const float*)d_in[12];
  const float* c1w  = (const float*)d_in[13];
  const float* c1b  = (const float*)d_in[14];
  float* out = (float*)d_out;
  float* ws  = (float*)d_ws;

  unsigned short* h0h = (unsigned short*)(ws + WS_H0B);
  unsigned short* h1h = (unsigned short*)(ws + WS_H1B);
  float* off_t   = ws + WS_OFFT;
  unsigned short* wtd  = (unsigned short*)(ws + WS_WTD);
  unsigned short* wtc  = (unsigned short*)(ws + WS_WTC);
  unsigned short* owtb = (unsigned short*)(ws + WS_OFFWTB);
  float* style0  = ws + WS_STYLE0;
  float* style1  = ws + WS_STYLE1;
  float* tproj   = ws + WS_TPROJ;
  float* mu0     = ws + WS_MU0;
  float* rs0     = ws + WS_RS0;
  float* gn1p    = ws + WS_GN1P;
  unsigned short* xh = (unsigned short*)(ws + WS_XH);

  prep_kernel<<<712, 256, 0, stream>>>(zemb, temb, g0w, g0b, g1w, g1b, d0w, d0b,
                                       dcnw, c1w, offw, x, wtd, wtc, owtb,
                                       style0, style1, tproj, mu0, rs0, xh);
  h0_kernel<<<4096, 256, 0, stream>>>(xh, style0, mu0, rs0, h0h);
  offset_mfma_kernel<<<1024, 512, 0, stream>>>(h0h, owtb, offb, off_t);
  deform_mfma_kernel<<<1024, 512, 0, stream>>>(h0h, off_t, wtd, dcnb, tproj, h1h, gn1p);
  conv1_mfma_kernel<<<1024, 512, 0, stream>>>(h1h, style1, gn1p, wtc, c1b, xh, out);
}

// Round 40
// 185.634 us; speedup vs baseline: 1.0121x; 1.0121x over previous
//
#include <hip/hip_runtime.h>
#include <hip/hip_bf16.h>

// ResnetBlockDDPMpp_Adagn: B=8, CIN=COUT=256, H=W=64, G=32, K=3
// Round 40: REVERT to R38 (185.7us, best verified).
//  - R39 lesson (failed, 187.9us): ASTR=264 (132 dwords = 4 mod 32) created
//    4.7M LDS bank conflicts on the b128 halo reads (272=136 dwords = 8 mod
//    32 interleaves cleanly with kc*32+g*8). And __launch_bounds__(512,6)
//    squeezed VGPR 64->40, adding dependency stalls; occupancy only 38->41%.
//    LDS-shave for conv1 requires a conflict-free stride AND free registers;
//    neither held. Reverted.
//  - This file == R38 byte-for-byte.

#define EPSV 1e-6f

typedef short    s16x8 __attribute__((ext_vector_type(8)));   // raw 8x16b storage
typedef _Float16 h16x8 __attribute__((ext_vector_type(8)));   // fp16 math/MFMA
typedef float    f32x4 __attribute__((ext_vector_type(4)));

__device__ __forceinline__ float silu_f(float v){ return v / (1.f + __expf(-v)); }
__device__ __forceinline__ unsigned short f2h(float f){
  _Float16 h = (_Float16)f; unsigned short u; __builtin_memcpy(&u, &h, 2); return u;
}
__device__ __forceinline__ float h2f(unsigned short u){
  _Float16 h; __builtin_memcpy(&h, &u, 2); return (float)h;
}

// ---------------- ws layout (float units) ----------------
#define WS_H0B     0            // 8*4096*256 fp16
#define WS_H1B     4194304      // 8*4096*256 fp16
#define WS_OFFT    8388608      // 8*4096*27 fp32
#define WS_WTD     9273344      // dcn fp16 [9][32][256][8]
#define WS_WTC     9568256      // conv1 fp16 same
#define WS_OFFWTB  9863168      // offw fp16 [9][32][32][8]
#define WS_STYLE0  9900032
#define WS_STYLE1  9904128
#define WS_TPROJ   9908224
#define WS_MU0     9910272
#define WS_RS0     9910528
#define WS_GN1P    9911296      // 8 b x 128 pblk x 64 = 65536 floats
#define WS_XH      9976832      // x as fp16 NCHW: 8388608 ushort = 4194304 floats
// end 14,171,136 floats = 56.7 MB (R4 proved 73.3MB OK)

#define SSTR 272   // LDS row stride (ushorts): 544B, 16B-aligned

// ---------- reductions ----------
__device__ __forceinline__ void block_reduce2(float& s, float& q){
  for (int off = 32; off > 0; off >>= 1) {
    s += __shfl_down(s, off, 64);
    q += __shfl_down(q, off, 64);
  }
  __shared__ float ss[4], qs[4];
  int wid = threadIdx.x >> 6, lane = threadIdx.x & 63;
  if (lane == 0) { ss[wid] = s; qs[wid] = q; }
  __syncthreads();
  if (threadIdx.x == 0) { s = ss[0]+ss[1]+ss[2]+ss[3]; q = qs[0]+qs[1]+qs[2]+qs[3]; }
}

// ---------- prep: coalesced weight packs + tiny GEMMs + gn0 stats + xh ----------
// grid 712: [0,64) dcn pack | [64,128) conv1 pack | [128,416) offw pack
//          [416,432) style0 | [432,448) style1 | [448,456) tproj | [456,712) gn0+xh
__global__ __launch_bounds__(256) void prep_kernel(
    const float* __restrict__ zemb, const float* __restrict__ temb,
    const float* __restrict__ g0w, const float* __restrict__ g0b,
    const float* __restrict__ g1w, const float* __restrict__ g1b,
    const float* __restrict__ d0w, const float* __restrict__ d0b,
    const float* __restrict__ dcn_w, const float* __restrict__ c1w,
    const float* __restrict__ offw, const float* __restrict__ x,
    unsigned short* __restrict__ wtd, unsigned short* __restrict__ wtc,
    unsigned short* __restrict__ offwtb,
    float* __restrict__ style0, float* __restrict__ style1, float* __restrict__ tproj,
    float* __restrict__ mu0, float* __restrict__ rs0,
    unsigned short* __restrict__ xh)
{
  __shared__ unsigned short lbuf[9216];   // 18KB: 4 o-rows of [256 c][9 k] fp16
  int blk = blockIdx.x, t = threadIdx.x;
  if (blk < 128) {                        // coalesced pack: dcn (blk<64) / conv1
    const float* src = (blk < 64) ? dcn_w : c1w;
    unsigned short* dst = (blk < 64) ? wtd : wtc;
    int o0 = (blk & 63) * 4;
    const float* sp = src + (size_t)o0 * 2304;   // 4 o-rows = 9216 floats, contiguous
    #pragma unroll
    for (int i = 0; i < 36; ++i) {        // phase 1: contiguous read -> LDS fp16
      int idx = i*256 + t;
      lbuf[idx] = f2h(sp[idx]);
    }
    __syncthreads();
    #pragma unroll
    for (int i = 0; i < 36; ++i) {        // phase 2: packed write, 64B runs
      int idx = i*256 + t;
      int kc8 = idx >> 5, m = idx & 31;
      int o = m >> 3, j = m & 7;
      int k = kc8 / 32, c8 = kc8 & 31;
      dst[((size_t)(k*32 + c8)*256 + (o0 + o))*8 + j] = lbuf[(o*256 + c8*8 + j)*9 + k];
    }
  } else if (blk < 416) {                 // offw pack: [9][32 c8][32 o][8 j], oc>=27 -> 0
    int e = (blk-128)*256 + t;            // 73728 elems
    int j = e & 7, o = (e >> 3) & 31, c8 = (e >> 8) & 31, k = e >> 13;
    int c = c8*8 + j;
    offwtb[e] = (o < 27) ? f2h(offw[((o*256 + c)*9) + k]) : (unsigned short)0;
  } else if (blk < 432) {                 // style0 = zemb @ g0w.T + g0b (8x512)
    int e = (blk-416)*256 + t; int b = e >> 9, j = e & 511;
    float s = g0b[j];
    const float* z = zemb + b*256; const float* w = g0w + j*256;
    for (int i = 0; i < 256; ++i) s += z[i]*w[i];
    style0[e] = s;
  } else if (blk < 448) {                 // style1
    int e = (blk-432)*256 + t; int b = e >> 9, j = e & 511;
    float s = g1b[j];
    const float* z = zemb + b*256; const float* w = g1w + j*256;
    for (int i = 0; i < 256; ++i) s += z[i]*w[i];
    style1[e] = s;
  } else if (blk < 456) {                 // tproj = silu(temb) @ d0w.T + d0b (one b/block)
    int b = blk - 448;
    float* st = (float*)lbuf;             // reuse 2KB of lbuf for silu(temb[b])
    const float* tb = temb + b*512;
    st[t]       = silu_f(tb[t]);
    st[t + 256] = silu_f(tb[t + 256]);
    __syncthreads();
    int o = t;
    float s = d0b[o];
    const float* w = d0w + o*512;
    for (int i = 0; i < 512; ++i) s += st[i]*w[i];
    tproj[b*256 + o] = s;
  } else {                                // gn0 stats + xh emit: blk2 = b*32+g (NCHW)
    int blk2 = blk - 456;                 // 256 blocks
    const float4* p4 = (const float4*)(x + (size_t)blk2*32768);
    unsigned short* xo = xh + (size_t)blk2*32768;
    float s = 0.f, q = 0.f;
    for (int i = t*2; i < 8192; i += 512) {   // 2 float4 reads + 1 s16x8 store
      float4 v0 = p4[i], v1 = p4[i+1];
      s += v0.x+v0.y+v0.z+v0.w + v1.x+v1.y+v1.z+v1.w;
      q += v0.x*v0.x + v0.y*v0.y + v0.z*v0.z + v0.w*v0.w
         + v1.x*v1.x + v1.y*v1.y + v1.z*v1.z + v1.w*v1.w;
      s16x8 pk;
      pk[0] = (short)f2h(v0.x); pk[1] = (short)f2h(v0.y);
      pk[2] = (short)f2h(v0.z); pk[3] = (short)f2h(v0.w);
      pk[4] = (short)f2h(v1.x); pk[5] = (short)f2h(v1.y);
      pk[6] = (short)f2h(v1.z); pk[7] = (short)f2h(v1.w);
      *(s16x8*)(xo + (size_t)i*4) = pk;
    }
    block_reduce2(s, q);
    if (t == 0) {
      float m = s * (1.f/32768.f);
      float var = q * (1.f/32768.f) - m*m;
      mu0[blk2] = m; rs0[blk2] = rsqrtf(var + EPSV);
    }
  }
}

// ---------- h0 = silu(adagn(xh)) NCHW -> NHWC fp16, vectorized ----------
#define HSTR 72    // LDS row stride (ushorts): 144B, 16B-aligned
__global__ __launch_bounds__(256) void h0_kernel(
    const unsigned short* __restrict__ xh, const float* __restrict__ style0,
    const float* __restrict__ mu, const float* __restrict__ rs,
    unsigned short* __restrict__ h0h)
{
  int blk = blockIdx.x;          // b(8) x ptile(64) x ctile(8)
  int b  = blk >> 9;
  int pt = (blk >> 3) & 63;
  int ct = blk & 7;
  __shared__ unsigned short sh[32*HSTR];   // 4.5KB fp16 tile
  int p0 = pt*64, c0 = ct*32;
  int t = threadIdx.x;
  {                              // read: 1 x ushort8 per thread (16B/lane)
    int ci = t >> 3;             // 0..31
    int pb = t & 7;              // p octet
    int c  = c0 + ci;
    s16x8 v8 = *(const s16x8*)&xh[((size_t)(b*256 + c))*4096 + p0 + pb*8];
    int g = c >> 3;
    float m  = mu[b*32+g], r = rs[b*32+g];
    float ga = style0[b*512 + c], be = style0[b*512 + 256 + c];
    s16x8 o8;
    #pragma unroll
    for (int j = 0; j < 8; ++j) {
      float v = h2f((unsigned short)v8[j]);
      float u = ga * (v - m) * r + be;
      o8[j] = (short)f2h(silu_f(u));
    }
    *(s16x8*)&sh[ci*HSTR + pb*8] = o8;
  }
  __syncthreads();
  {                              // write: 1 x ushort8 per thread (16B/lane)
    int p  = t >> 2;             // 0..63
    int co = (t & 3)*8;          // c octet
    s16x8 o8;
    #pragma unroll
    for (int j = 0; j < 8; ++j) o8[j] = (short)sh[(co + j)*HSTR + p];
    *(s16x8*)&h0h[((size_t)(b*4096 + p0 + p))*256 + c0 + co] = o8;
  }
}

// ---------- offset conv MFMA (fp16): 512 thr, kc-split waves, 32 px x 32 oc ----------
__global__ __launch_bounds__(512, 2) void offset_mfma_kernel(
    const unsigned short* __restrict__ h0h, const unsigned short* __restrict__ wt,
    const float* __restrict__ off_b, float* __restrict__ off_t)
{
  int bid = blockIdx.x;
  int b  = bid & 7;                            // XCD swizzle
  int p0 = (bid >> 3) * 32;
  int y = p0 >> 6, xb = p0 & 63;
  int t = threadIdx.x;                         // 0..511
  int lane = t & 63, wv = t >> 6;              // 8 waves
  int r = lane & 15, g = lane >> 4;

  __shared__ unsigned short aw[3*34*SSTR];     // 55.5KB
  __shared__ f32x4 pacc[4][64];                // 4KB kc-split partials -> 59.6KB

  const unsigned short* hbase = h0h + (size_t)b*1048576;
  for (int idx = t; idx < 3264; idx += 512) {
    int row = idx / 1088, rem = idx - row*1088;
    int px = rem >> 5, c8 = rem & 31;
    int yy = y + row - 1, xx = xb - 1 + px;
    s16x8 v = {0,0,0,0,0,0,0,0};
    if (yy >= 0 && yy < 64 && xx >= 0 && xx < 64)
      v = *(const s16x8*)&hbase[((size_t)yy*64 + xx)*256 + c8*8];
    *(s16x8*)&aw[(row*34 + px)*SSTR + c8*8] = v;
  }
  __syncthreads();

  int m = wv & 1, n = (wv >> 1) & 1, h = wv >> 2;   // tile (px half, oc half), kc half
  f32x4 acc = {0.f,0.f,0.f,0.f};
  for (int k = 0; k < 9; ++k) {
    int ky = k/3, kxo = k%3;
    const unsigned short* abase = &aw[(ky*34)*SSTR];
    const unsigned short* wk = wt + (size_t)k*8192;   // [32 c8][32 o][8]
    #pragma unroll
    for (int kc2 = 0; kc2 < 4; ++kc2) {
      int kc = h*4 + kc2;
      h16x8 a  = *(const h16x8*)&abase[(kxo + m*16 + r)*SSTR + kc*32 + g*8];
      h16x8 bf = *(const h16x8*)&wk[(size_t)((kc*4 + g)*32 + n*16 + r)*8];
      acc = __builtin_amdgcn_mfma_f32_16x16x32_f16(a, bf, acc, 0, 0, 0);
    }
  }

  int tile = wv & 3;
  if (h == 1) pacc[tile][lane] = acc;
  __syncthreads();
  if (h == 0) {
    acc = acc + pacc[tile][lane];                // fixed 2-term association
    int oc = n*16 + r;
    if (oc < 27) {
      float bs = off_b[oc];
      #pragma unroll
      for (int j = 0; j < 4; ++j) {
        int px = m*16 + g*4 + j;
        off_t[((size_t)(b*4096) + p0 + px)*27 + oc] = acc[j] + bs;
      }
    }
  }
}

// ---------- deformable conv (fp16): M=32, pre[8] resident, fused gn1 partials ----------
__global__ __launch_bounds__(512, 2) void deform_mfma_kernel(
    const unsigned short* __restrict__ h0h, const float* __restrict__ off_t,
    const unsigned short* __restrict__ wt, const float* __restrict__ dcn_b,
    const float* __restrict__ tproj, unsigned short* __restrict__ h1h,
    float* __restrict__ part)
{
  int bid = blockIdx.x;                        // 1024 blocks
  int b  = bid & 7;                            // XCD swizzle (1024 % 8 == 0)
  int p0 = (bid >> 3) * 32;                    // 32 px, same row
  int t = threadIdx.x;                         // 0..511
  int lane = t & 63, wv = t >> 6;              // 8 waves
  int r = lane & 15, g = lane >> 4;

  __shared__ unsigned short samp[2][32*SSTR];  // dbuf 34.8KB
  __shared__ int    pki[288];
  __shared__ float4 pkw[288];                  // total 40.6KB -> 4 blk/CU

  for (int tp = t; tp < 288; tp += 512) {      // 32 px x 9 taps
    int i = tp / 9, k = tp - i*9;
    int p = p0 + i; int y = p >> 6, xq = p & 63;
    const float* ob = off_t + ((size_t)(b*4096) + p)*27;
    float dy = ob[2*k], dx = ob[2*k+1];
    float mask = 1.f / (1.f + __expf(-ob[18+k]));
    float py = dy + (float)(k/3 + y - 1);
    float px = dx + (float)(k%3 + xq - 1);
    float fy0 = floorf(py), fx0 = floorf(px);
    float wy1 = py - fy0, wx1 = px - fx0;
    int y0 = (int)fy0, x0 = (int)fx0, y1 = y0+1, x1 = x0+1;
    float vy0 = (y0 >= 0 && y0 < 64) ? 1.f : 0.f;
    float vy1 = (y1 >= 0 && y1 < 64) ? 1.f : 0.f;
    float vx0 = (x0 >= 0 && x0 < 64) ? 1.f : 0.f;
    float vx1 = (x1 >= 0 && x1 < 64) ? 1.f : 0.f;
    int iy0 = min(max(y0,0),63), ix0 = min(max(x0,0),63);
    int iy1 = min(max(y1,0),63), ix1 = min(max(x1,0),63);
    pki[tp] = iy0 | (ix0 << 8) | (iy1 << 16) | (ix1 << 24);
    float4 w;
    w.x = (1.f-wy1)*(1.f-wx1)*vy0*vx0*mask;
    w.y = (1.f-wy1)*wx1      *vy0*vx1*mask;
    w.z = wy1      *(1.f-wx1)*vy1*vx0*mask;
    w.w = wy1      *wx1      *vy1*vx1*mask;
    pkw[tp] = w;
  }
  __syncthreads();

  f32x4 zero4 = {0.f,0.f,0.f,0.f};
  f32x4 acc[2][2];
  #pragma unroll
  for (int m = 0; m < 2; ++m) { acc[m][0] = zero4; acc[m][1] = zero4; }

  const unsigned short* hb = h0h + (size_t)b*1048576;
  int px = t >> 4;                             // 16 threads per pixel (32 px)
  int ci = (t & 15) * 16;                      // 16 contiguous channels each
  int o_base = wv*32 + r;                      // 8 waves x UNIQUE 32-out slice

  h16x8 pre[8];                                // 4 corners x 16ch = 32 VGPR
  auto loadk = [&](int kk) {
    int tp = px*9 + kk;
    int pk = pki[tp];
    int iy0 = pk & 255, ix0 = (pk >> 8) & 255, iy1 = (pk >> 16) & 255, ix1 = (pk >> 24) & 255;
    const h16x8* q00 = (const h16x8*)(hb + ((size_t)iy0*64 + ix0)*256 + ci);
    const h16x8* q01 = (const h16x8*)(hb + ((size_t)iy0*64 + ix1)*256 + ci);
    const h16x8* q10 = (const h16x8*)(hb + ((size_t)iy1*64 + ix0)*256 + ci);
    const h16x8* q11 = (const h16x8*)(hb + ((size_t)iy1*64 + ix1)*256 + ci);
    pre[0] = q00[0]; pre[1] = q00[1];
    pre[2] = q01[0]; pre[3] = q01[1];
    pre[4] = q10[0]; pre[5] = q10[1];
    pre[6] = q11[0]; pre[7] = q11[1];
  };

  loadk(0);
  for (int k = 0; k < 9; ++k) {
    { // pk-fma weighted sum from prefetch regs -> LDS buf k&1
      int tp = px*9 + k;
      float4 w = pkw[tp];
      _Float16 w00 = (_Float16)w.x, w01 = (_Float16)w.y;
      _Float16 w10 = (_Float16)w.z, w11 = (_Float16)w.w;
      unsigned short* sp = &samp[k & 1][px*SSTR + ci];
      #pragma unroll
      for (int ch = 0; ch < 2; ++ch) {
        h16x8 o = pre[ch]*w00 + pre[2+ch]*w01 + pre[4+ch]*w10 + pre[6+ch]*w11;
        *(h16x8*)(sp + ch*8) = o;
      }
    }
    if (k < 8) loadk(k+1);                     // pre[8] stays resident
    asm volatile("s_waitcnt lgkmcnt(0)" ::: "memory");
    __builtin_amdgcn_s_barrier();

    const unsigned short* sb = samp[k & 1];
    const unsigned short* wk = wt + (size_t)k*65536;   // [32][256][8] this tap
    #pragma unroll
    for (int kc = 0; kc < 8; ++kc) {
      h16x8 a0 = *(const h16x8*)&sb[(     r)*SSTR + kc*32 + g*8];
      h16x8 a1 = *(const h16x8*)&sb[(16 + r)*SSTR + kc*32 + g*8];
      const unsigned short* wb = wk + (size_t)(kc*4 + g)*2048 + o_base*8;
      h16x8 b0 = *(const h16x8*)&wb[  0*8];
      h16x8 b1 = *(const h16x8*)&wb[ 16*8];
      acc[0][0] = __builtin_amdgcn_mfma_f32_16x16x32_f16(a0, b0, acc[0][0], 0, 0, 0);
      acc[0][1] = __builtin_amdgcn_mfma_f32_16x16x32_f16(a0, b1, acc[0][1], 0, 0, 0);
      acc[1][0] = __builtin_amdgcn_mfma_f32_16x16x32_f16(a1, b0, acc[1][0], 0, 0, 0);
      acc[1][1] = __builtin_amdgcn_mfma_f32_16x16x32_f16(a1, b1, acc[1][1], 0, 0, 0);
    }
    // no second barrier: next tap writes the other buffer (WAR safe)
  }

  // epilogue: h1 write + fused gn1 partials (on the exact fp16-rounded values)
  float gs[2], gq[2];
  #pragma unroll
  for (int nn = 0; nn < 2; ++nn) {
    int o = o_base + nn*16;
    float bs = dcn_b[o] + tproj[b*256 + o];
    float s = 0.f, q = 0.f;
    #pragma unroll
    for (int m = 0; m < 2; ++m)
      #pragma unroll
      for (int j = 0; j < 4; ++j) {
        int pxl = m*16 + g*4 + j;
        unsigned short hu = f2h(acc[m][nn][j] + bs);
        h1h[((size_t)(b*4096) + p0 + pxl)*256 + o] = hu;
        float f = h2f(hu);
        s += f; q += f*f;
      }
    // cross-g reduce: lanes r, r+16, r+32, r+48 (same wave), fixed order
    s += __shfl_down(s, 16, 64); s += __shfl_down(s, 32, 64);
    q += __shfl_down(q, 16, 64); q += __shfl_down(q, 32, 64);
    gs[nn] = s; gq[nn] = q;
  }
  __syncthreads();                             // all samp/pkw consumers done
  float* sred = (float*)samp;                  // reuse dead LDS (2KB needed)
  float* qred = sred + 256;
  if (g == 0) {
    #pragma unroll
    for (int nn = 0; nn < 2; ++nn) {
      int o = o_base + nn*16;
      sred[o] = gs[nn]; qred[o] = gq[nn];
    }
  }
  __syncthreads();
  if (t < 32) {                                // fold 8 channels -> group partial
    float s = 0.f, q = 0.f;
    #pragma unroll
    for (int j = 0; j < 8; ++j) { s += sred[t*8 + j]; q += qred[t*8 + j]; }
    int pblk = bid >> 3;
    part[((size_t)(b*128 + pblk))*64 + t]      = s;
    part[((size_t)(b*128 + pblk))*64 + 32 + t] = q;
  }
}

// ---------- conv1 (fp16) M=32, fused gn1-finalize (parallel fold) + adagn/silu ----------
__global__ __launch_bounds__(512, 2) void conv1_mfma_kernel(
    const unsigned short* __restrict__ h1h, const float* __restrict__ style1,
    const float* __restrict__ part,
    const unsigned short* __restrict__ wt,
    const float* __restrict__ c1_b, const unsigned short* __restrict__ xh,
    float* __restrict__ out)
{
  int bid = blockIdx.x;                        // 1024 blocks
  int b  = bid & 7;                            // XCD swizzle
  int p0 = (bid >> 3) * 32;
  int y = p0 >> 6, xb = p0 & 63;
  int t = threadIdx.x;                         // 0..511
  int lane = t & 63, wv = t >> 6;              // 8 waves
  int r = lane & 15, g = lane >> 4;

  __shared__ unsigned short aw[3*34*SSTR];     // 55.5KB
  __shared__ float smu[32], srs[32];
  __shared__ float fls[512], flq[512];         // +4KB fold scratch -> 59.6KB, 2 blk/CU

  // gn1 finalize, parallel: thread (s=t>>5, g2=t&31) sums 8 block-partials
  {
    int s = t >> 5, g2 = t & 31;
    float fs = 0.f, fq = 0.f;
    #pragma unroll
    for (int c = 0; c < 8; ++c) {
      int ch = s*8 + c;
      fs += part[(b*128 + ch)*64 + g2];
      fq += part[(b*128 + ch)*64 + 32 + g2];
    }
    fls[s*32 + g2] = fs; flq[s*32 + g2] = fq;
  }
  __syncthreads();
  if (t < 32) {                                // fixed-order 16-slice reduce
    float s2 = 0.f, q2 = 0.f;
    #pragma unroll
    for (int sl = 0; sl < 16; ++sl) { s2 += fls[sl*32 + t]; q2 += flq[sl*32 + t]; }
    float m = s2 * (1.f/32768.f);
    float var = q2 * (1.f/32768.f) - m*m;
    smu[t] = m; srs[t] = rsqrtf(var + EPSV);
  }
  __syncthreads();

  const unsigned short* h1base = h1h + (size_t)b*1048576;
  for (int idx = t; idx < 3264; idx += 512) {  // 3 rows * 34 px * 32 chunks(8c)
    int row = idx / 1088, rem = idx - row*1088;
    int px = rem >> 5, c8 = rem & 31;
    int yy = y + row - 1, xx = xb - 1 + px;
    s16x8 v = {0,0,0,0,0,0,0,0};
    if (yy >= 0 && yy < 64 && xx >= 0 && xx < 64) {
      s16x8 h = *(const s16x8*)&h1base[((size_t)yy*64 + xx)*256 + c8*8];
      float m  = smu[c8], rr = srs[c8];
      #pragma unroll
      for (int j = 0; j < 8; ++j) {
        int c = c8*8 + j;
        float ga = style1[b*512 + c], be = style1[b*512 + 256 + c];
        float u = ga * (h2f((unsigned short)h[j]) - m) * rr + be;
        v[j] = (short)f2h(silu_f(u));
      }
    }
    *(s16x8*)&aw[(row*34 + px)*SSTR + c8*8] = v;
  }
  __syncthreads();

  f32x4 zero4 = {0.f,0.f,0.f,0.f};
  f32x4 acc[2][2];
  #pragma unroll
  for (int m = 0; m < 2; ++m) { acc[m][0] = zero4; acc[m][1] = zero4; }

  int o_base = wv*32 + r;                      // 8 waves x UNIQUE 32-out slice
  for (int k = 0; k < 9; ++k) {
    int ky = k/3, kxo = k%3;
    const unsigned short* abase = &aw[(ky*34)*SSTR];
    const unsigned short* wk = wt + (size_t)k*65536;
    #pragma unroll
    for (int kc = 0; kc < 8; ++kc) {
      h16x8 a0 = *(const h16x8*)&abase[(kxo +      r)*SSTR + kc*32 + g*8];
      h16x8 a1 = *(const h16x8*)&abase[(kxo + 16 + r)*SSTR + kc*32 + g*8];
      const unsigned short* wb = wk + (size_t)(kc*4 + g)*2048 + o_base*8;
      h16x8 b0 = *(const h16x8*)&wb[  0*8];
      h16x8 b1 = *(const h16x8*)&wb[ 16*8];
      acc[0][0] = __builtin_amdgcn_mfma_f32_16x16x32_f16(a0, b0, acc[0][0], 0, 0, 0);
      acc[0][1] = __builtin_amdgcn_mfma_f32_16x16x32_f16(a0, b1, acc[0][1], 0, 0, 0);
      acc[1][0] = __builtin_amdgcn_mfma_f32_16x16x32_f16(a1, b0, acc[1][0], 0, 0, 0);
      acc[1][1] = __builtin_amdgcn_mfma_f32_16x16x32_f16(a1, b1, acc[1][1], 0, 0, 0);
    }
  }

  #pragma unroll
  for (int nn = 0; nn < 2; ++nn) {
    int o = o_base + nn*16;
    float cb = c1_b[o];
    #pragma unroll
    for (int m = 0; m < 2; ++m)
      #pragma unroll
      for (int j = 0; j < 4; ++j) {
        int pxl = m*16 + g*4 + j;
        size_t oi = ((size_t)(b*256 + o))*4096 + p0 + pxl;
        out[oi] = h2f(xh[oi]) + acc[m][nn][j] + cb;
      }
  }
}

extern "C" void kernel_launch(void* const* d_in, const int* in_sizes, int n_in,
                              void* d_out, int out_size, void* d_ws, size_t ws_size,
                              hipStream_t stream) {
  const float* x    = (const float*)d_in[0];
  const float* temb = (const float*)d_in[1];
  const float* zemb = (const float*)d_in[2];
  const float* g0w  = (const float*)d_in[3];
  const float* g0b  = (const float*)d_in[4];
  const float* offw = (const float*)d_in[5];
  const float* offb = (const float*)d_in[6];
  const float* dcnw = (const float*)d_in[7];
  const float* dcnb = (const float*)d_in[8];
  const float* d0w  = (const float*)d_in[9];
  const float* d0b  = (const float*)d_in[10];
  const float* g1w  = (const float*)d_in[11];
  const float* g1b  = (const float*)d_in[12];
  const float* c1w  = (const float*)d_in[13];
  const float* c1b  = (const float*)d_in[14];
  float* out = (float*)d_out;
  float* ws  = (float*)d_ws;

  unsigned short* h0h = (unsigned short*)(ws + WS_H0B);
  unsigned short* h1h = (unsigned short*)(ws + WS_H1B);
  float* off_t   = ws + WS_OFFT;
  unsigned short* wtd  = (unsigned short*)(ws + WS_WTD);
  unsigned short* wtc  = (unsigned short*)(ws + WS_WTC);
  unsigned short* owtb = (unsigned short*)(ws + WS_OFFWTB);
  float* style0  = ws + WS_STYLE0;
  float* style1  = ws + WS_STYLE1;
  float* tproj   = ws + WS_TPROJ;
  float* mu0     = ws + WS_MU0;
  float* rs0     = ws + WS_RS0;
  float* gn1p    = ws + WS_GN1P;
  unsigned short* xh = (unsigned short*)(ws + WS_XH);

  prep_kernel<<<712, 256, 0, stream>>>(zemb, temb, g0w, g0b, g1w, g1b, d0w, d0b,
                                       dcnw, c1w, offw, x, wtd, wtc, owtb,
                                       style0, style1, tproj, mu0, rs0, xh);
  h0_kernel<<<4096, 256, 0, stream>>>(xh, style0, mu0, rs0, h0h);
  offset_mfma_kernel<<<1024, 512, 0, stream>>>(h0h, owtb, offb, off_t);
  deform_mfma_kernel<<<1024, 512, 0, stream>>>(h0h, off_t, wtd, dcnb, tproj, h1h, gn1p);
  conv1_mfma_kernel<<<1024, 512, 0, stream>>>(h1h, style1, gn1p, wtc, c1b, xh, out);
}